// Round 1
// baseline (912.023 us; speedup 1.0000x reference)
//
#include <hip/hip_runtime.h>
#include <cstdint>

#define BATCH 2048
#define TLEN  2048
#define NC    5

// identity backpointer packing: j at bits 3j
#define IDENT_PACK ((uint16_t)(0 | (1<<3) | (2<<6) | (3<<9) | (4<<12)))

__global__ __launch_bounds__(64) void crf_viterbi_kernel(
    const float* __restrict__ x,          // (B,T,C) f32
    const int*   __restrict__ mask,       // (B,T) i32
    const float* __restrict__ transform,  // (C+2,C+2) f32
    float*       __restrict__ out,        // [B] scores, then [B*T] path (as f32)
    uint16_t*    __restrict__ bp_ws)      // (B,T) packed backpointers
{
    int b = blockIdx.x * blockDim.x + threadIdx.x;
    if (b >= BATCH) return;

    // transform pieces (uniform across threads -> scalar loads)
    float trans[NC][NC];
#pragma unroll
    for (int i = 0; i < NC; ++i)
#pragma unroll
        for (int j = 0; j < NC; ++j)
            trans[i][j] = transform[i * (NC + 2) + j];
    float tstart[NC], tend[NC];
#pragma unroll
    for (int j = 0; j < NC; ++j) tstart[j] = transform[NC * (NC + 2) + j];
#pragma unroll
    for (int j = 0; j < NC; ++j) tend[j]   = transform[j * (NC + 2) + (NC + 1)];

    const float* xb  = x    + (size_t)b * TLEN * NC;
    const int*   mb  = mask + (size_t)b * TLEN;
    uint16_t*    bpb = bp_ws + (size_t)b * TLEN;

    // dp0 = x[:,0,:] + transform[START,:C]
    float dp[NC];
#pragma unroll
    for (int j = 0; j < NC; ++j) dp[j] = xb[j] + tstart[j];

#pragma unroll 4
    for (int t = 1; t < TLEN; ++t) {
        float xt[NC];
#pragma unroll
        for (int j = 0; j < NC; ++j) xt[j] = xb[t * NC + j];
        int mt = mb[t];

        float ndp[NC];
        int   bp[NC];
#pragma unroll
        for (int j = 0; j < NC; ++j) {
            float best = dp[0] + trans[0][j];
            int   arg  = 0;
#pragma unroll
            for (int i = 1; i < NC; ++i) {
                float sc = dp[i] + trans[i][j];
                if (sc > best) { best = sc; arg = i; }   // strict > == first-max (jnp.argmax)
            }
            ndp[j] = best + xt[j];
            bp[j]  = arg;
        }

        uint16_t packed;
        if (mt) {
            packed = (uint16_t)(bp[0] | (bp[1] << 3) | (bp[2] << 6) |
                                (bp[3] << 9) | (bp[4] << 12));
#pragma unroll
            for (int j = 0; j < NC; ++j) dp[j] = ndp[j];
        } else {
            packed = IDENT_PACK;   // bp_out = arange(C), dp unchanged
        }
        bpb[t] = packed;
    }

    // final = dp + transform[:C, END]; max & first-argmax
    float best = dp[0] + tend[0];
    int   last = 0;
#pragma unroll
    for (int j = 1; j < NC; ++j) {
        float sc = dp[j] + tend[j];
        if (sc > best) { best = sc; last = j; }
    }
    out[b] = best;

    // backtrack: path[T-1] = last; path[t-1] = bp[t][path[t]]
    float* path = out + BATCH + (size_t)b * TLEN;
    int idx = last;
    for (int t = TLEN - 1; t >= 1; --t) {
        path[t] = (float)idx;
        int p = bpb[t];
        idx = (p >> (3 * idx)) & 7;
    }
    path[0] = (float)idx;
}

extern "C" void kernel_launch(void* const* d_in, const int* in_sizes, int n_in,
                              void* d_out, int out_size, void* d_ws, size_t ws_size,
                              hipStream_t stream) {
    const float* x         = (const float*)d_in[0];
    const int*   mask      = (const int*)d_in[1];
    const float* transform = (const float*)d_in[2];
    float*       out       = (float*)d_out;
    uint16_t*    bp_ws     = (uint16_t*)d_ws;   // needs B*T*2 = 8 MiB

    dim3 block(64);
    dim3 grid((BATCH + 63) / 64);   // 32 blocks -> spread across CUs
    hipLaunchKernelGGL(crf_viterbi_kernel, grid, block, 0, stream,
                       x, mask, transform, out, bp_ws);
}

// Round 2
// 770.889 us; speedup vs baseline: 1.1831x; 1.1831x over previous
//
#include <hip/hip_runtime.h>
#include <cstdint>

#define B_   2048
#define T_   2048
#define TD   7            // transform leading dim (C+2)
#define S_   128          // backtrack segments
#define LS   16           // segment length (S_*LS == T_)
#define BLK  8            // forward register block (steps)
#define NBLK (T_/BLK)     // 256
#define IDENT 0x4688u     // 0|1<<3|2<<6|3<<9|4<<12

// ---------------- forward (exact, sequential per batch) ----------------

template<int LSTART>
__device__ __forceinline__ void proc_block(
    const float4 (&X)[10], const int4 (&M)[2],
    float (&dp)[5], const float (&tr)[5][5],
    uint16_t* __restrict__ dst)
{
    float xf[BLK * 5];
#pragma unroll
    for (int q = 0; q < 10; ++q) {
        xf[4*q+0] = X[q].x; xf[4*q+1] = X[q].y;
        xf[4*q+2] = X[q].z; xf[4*q+3] = X[q].w;
    }
    int ml[BLK];
#pragma unroll
    for (int q = 0; q < 2; ++q) {
        ml[4*q+0] = M[q].x; ml[4*q+1] = M[q].y;
        ml[4*q+2] = M[q].z; ml[4*q+3] = M[q].w;
    }

    uint32_t acc[BLK/2];
#pragma unroll
    for (int q = 0; q < BLK/2; ++q) acc[q] = 0;

#pragma unroll
    for (int l = 0; l < BLK; ++l) {
        uint32_t pk;
        if (l < LSTART) {
            pk = IDENT;                    // t==0 slot, never read
        } else {
            const bool mm = (ml[l] != 0);
            float nd[5]; uint32_t pc = 0;
#pragma unroll
            for (int j = 0; j < 5; ++j) {
                float s0 = dp[0] + tr[0][j];
                float s1 = dp[1] + tr[1][j];
                float s2 = dp[2] + tr[2][j];
                float s3 = dp[3] + tr[3][j];
                float s4 = dp[4] + tr[4][j];
                float m = fmaxf(fmaxf(fmaxf(s0, s1), fmaxf(s2, s3)), s4);
                // first-match == reference's ascending strict-> argmax (exact)
                int a = (s0 == m) ? 0 : ((s1 == m) ? 1 : ((s2 == m) ? 2 : ((s3 == m) ? 3 : 4)));
                nd[j] = m + xf[5*l + j];
                pc |= ((uint32_t)a) << (3*j);
            }
#pragma unroll
            for (int j = 0; j < 5; ++j) dp[j] = mm ? nd[j] : dp[j];
            pk = mm ? pc : IDENT;
        }
        acc[l >> 1] |= pk << (16 * (l & 1));
    }
    uint4 st; st.x = acc[0]; st.y = acc[1]; st.z = acc[2]; st.w = acc[3];
    *(uint4*)dst = st;
}

__global__ __launch_bounds__(64, 1) void kf(
    const float* __restrict__ x, const int* __restrict__ mask,
    const float* __restrict__ transform,
    float* __restrict__ out, uint16_t* __restrict__ bp, int* __restrict__ lastc)
{
    int b = blockIdx.x * 64 + threadIdx.x;

    float tr[5][5];
#pragma unroll
    for (int i = 0; i < 5; ++i)
#pragma unroll
        for (int j = 0; j < 5; ++j) tr[i][j] = transform[i*TD + j];

    const float* xb  = x + (size_t)b * (T_*5);
    const int*   mb  = mask + (size_t)b * T_;
    uint16_t*    bpb = bp + (size_t)b * T_;

    float dp[5];
#pragma unroll
    for (int j = 0; j < 5; ++j) dp[j] = xb[j] + transform[5*TD + j];

    float4 XA[10], XB[10]; int4 MA[2], MB[2];

    auto LOADX = [&](float4 (&X)[10], int4 (&M)[2], int kk) {
        const float4* px = (const float4*)(xb + (size_t)kk * (BLK*5));
#pragma unroll
        for (int q = 0; q < 10; ++q) X[q] = px[q];
        const int4* pm = (const int4*)(mb + kk * BLK);
#pragma unroll
        for (int q = 0; q < 2; ++q) M[q] = pm[q];
    };

    LOADX(XA, MA, 0);
    LOADX(XB, MB, 1);
    proc_block<1>(XA, MA, dp, tr, bpb);            // block 0 (skips t=0)
    for (int k = 1; k < NBLK - 1; k += 2) {
        LOADX(XA, MA, k + 1);
        proc_block<0>(XB, MB, dp, tr, bpb + (size_t)k * BLK);
        LOADX(XB, MB, k + 2);
        proc_block<0>(XA, MA, dp, tr, bpb + (size_t)(k + 1) * BLK);
    }
    proc_block<0>(XB, MB, dp, tr, bpb + (size_t)(NBLK - 1) * BLK);

    float best = dp[0] + transform[0*TD + 6];
    int   last = 0;
#pragma unroll
    for (int j = 1; j < 5; ++j) {
        float sc = dp[j] + transform[j*TD + 6];
        if (sc > best) { best = sc; last = j; }
    }
    out[b]   = best;
    lastc[b] = last;
}

// ---------------- backtrack (exact integer maps, parallel) ----------------

// per (b,s): sigma = map class@segment-end -> class@segment-start-1
__global__ __launch_bounds__(256) void ks(
    const uint16_t* __restrict__ bp, uint16_t* __restrict__ sigma)
{
    int tid = blockIdx.x * 256 + threadIdx.x;
    int b = tid >> 7, s = tid & (S_ - 1);
    const uint4 w = *(const uint4*)(bp + (size_t)b * T_ + s * LS);
    uint32_t ww[4] = { w.x, w.y, w.z, w.w };
    int i0 = 0, i1 = 1, i2 = 2, i3 = 3, i4 = 4;
#pragma unroll
    for (int l = LS - 1; l >= 0; --l) {
        uint32_t p = (ww[l >> 1] >> (16 * (l & 1))) & 0xFFFFu;
        i0 = (p >> (3*i0)) & 7;
        i1 = (p >> (3*i1)) & 7;
        i2 = (p >> (3*i2)) & 7;
        i3 = (p >> (3*i3)) & 7;
        i4 = (p >> (3*i4)) & 7;
    }
    sigma[(size_t)s * B_ + b] =
        (uint16_t)(i0 | (i1 << 3) | (i2 << 6) | (i3 << 9) | (i4 << 12));
}

// per b: scan segments backward -> class at each segment end
__global__ __launch_bounds__(64) void kscan(
    const int* __restrict__ lastc, const uint16_t* __restrict__ sigma,
    uint8_t* __restrict__ endcls)
{
    int b = blockIdx.x * 64 + threadIdx.x;
    int c = lastc[b];
    for (int s = S_ - 1; s >= 0; --s) {
        endcls[(size_t)s * B_ + b] = (uint8_t)c;
        c = (sigma[(size_t)s * B_ + b] >> (3*c)) & 7;
    }
}

// per (b,s): write path floats for the segment
__global__ __launch_bounds__(256) void kpath(
    const uint16_t* __restrict__ bp, const uint8_t* __restrict__ endcls,
    float* __restrict__ out)
{
    int tid = blockIdx.x * 256 + threadIdx.x;
    int b = tid >> 7, s = tid & (S_ - 1);
    int idx = endcls[(size_t)s * B_ + b];
    const uint4 w = *(const uint4*)(bp + (size_t)b * T_ + s * LS);
    uint32_t ww[4] = { w.x, w.y, w.z, w.w };
    float pv[LS];
#pragma unroll
    for (int l = LS - 1; l >= 0; --l) {
        pv[l] = (float)idx;
        uint32_t p = (ww[l >> 1] >> (16 * (l & 1))) & 0xFFFFu;
        idx = (p >> (3*idx)) & 7;   // at t==0 this is IDENT (harmless)
    }
    float* path = out + B_ + (size_t)b * T_ + s * LS;
#pragma unroll
    for (int q = 0; q < 4; ++q) {
        float4 v; v.x = pv[4*q]; v.y = pv[4*q+1]; v.z = pv[4*q+2]; v.w = pv[4*q+3];
        ((float4*)path)[q] = v;
    }
}

extern "C" void kernel_launch(void* const* d_in, const int* in_sizes, int n_in,
                              void* d_out, int out_size, void* d_ws, size_t ws_size,
                              hipStream_t stream) {
    const float* x         = (const float*)d_in[0];
    const int*   mask      = (const int*)d_in[1];
    const float* transform = (const float*)d_in[2];
    float*       out       = (float*)d_out;

    uint8_t* wsb = (uint8_t*)d_ws;
    uint16_t* bp    = (uint16_t*)wsb;                                   // 8 MiB
    uint16_t* sigma = (uint16_t*)(wsb + (8u << 20));                    // 512 KiB
    uint8_t*  endc  = wsb + (8u << 20) + (512u << 10);                  // 256 KiB
    int*      lastc = (int*)(wsb + (8u << 20) + (768u << 10));          // 8 KiB

    hipLaunchKernelGGL(kf,    dim3(B_/64),        dim3(64),  0, stream,
                       x, mask, transform, out, bp, lastc);
    hipLaunchKernelGGL(ks,    dim3(B_*S_/256),    dim3(256), 0, stream, bp, sigma);
    hipLaunchKernelGGL(kscan, dim3(B_/64),        dim3(64),  0, stream,
                       lastc, sigma, endc);
    hipLaunchKernelGGL(kpath, dim3(B_*S_/256),    dim3(256), 0, stream,
                       bp, endc, out);
}

// Round 3
// 116.476 us; speedup vs baseline: 7.8301x; 6.6184x over previous
//
#include <hip/hip_runtime.h>
#include <cstdint>

#define B_    2048
#define T_    2048
#define TD    7            // transform leading dim (C+2)
#define NCH   32           // chunks over T
#define L_    64           // chunk length (NCH*L_ == T_)
#define NB    8            // 8-step sub-blocks per chunk
#define IDENT 0x4688u      // 0|1<<3|2<<6|3<<9|4<<12

// ---- 8-step vector loader (x: 10x float4, mask: 2x int4) ----
__device__ __forceinline__ void loadx(const float* __restrict__ xb,
                                      const int* __restrict__ mb, int kk,
                                      float4 (&X)[10], int4 (&M)[2]) {
    const float4* px = (const float4*)(xb + (size_t)kk * 40);
#pragma unroll
    for (int q = 0; q < 10; ++q) X[q] = px[q];
    const int4* pm = (const int4*)(mb + kk * 8);
#pragma unroll
    for (int q = 0; q < 2; ++q) M[q] = pm[q];
}

// ---- max-plus operator composition over 8 steps ----
template<int LSTART>
__device__ __forceinline__ void compose_block(
    const float4 (&X)[10], const int4 (&M)[2],
    float (&A)[5][5], const float (&tr)[5][5])
{
    float xf[40];
#pragma unroll
    for (int q = 0; q < 10; ++q) {
        xf[4*q] = X[q].x; xf[4*q+1] = X[q].y; xf[4*q+2] = X[q].z; xf[4*q+3] = X[q].w;
    }
    int ml[8];
#pragma unroll
    for (int q = 0; q < 2; ++q) {
        ml[4*q] = M[q].x; ml[4*q+1] = M[q].y; ml[4*q+2] = M[q].z; ml[4*q+3] = M[q].w;
    }
#pragma unroll
    for (int l = 0; l < 8; ++l) {
        if (l < LSTART) continue;
        const bool mm = (ml[l] != 0);
        float Tt[5][5];
#pragma unroll
        for (int k = 0; k < 5; ++k)
#pragma unroll
            for (int j = 0; j < 5; ++j) Tt[k][j] = tr[k][j] + xf[5*l + j];
#pragma unroll
        for (int i = 0; i < 5; ++i) {
            float nr[5];
#pragma unroll
            for (int j = 0; j < 5; ++j) {
                float v = A[i][0] + Tt[0][j];
                v = fmaxf(v, A[i][1] + Tt[1][j]);
                v = fmaxf(v, A[i][2] + Tt[2][j]);
                v = fmaxf(v, A[i][3] + Tt[3][j]);
                v = fmaxf(v, A[i][4] + Tt[4][j]);
                nr[j] = v;
            }
#pragma unroll
            for (int j = 0; j < 5; ++j) A[i][j] = mm ? nr[j] : A[i][j];
        }
    }
}

// ---- exact forward over 8 steps, packed backpointer store ----
template<int LSTART>
__device__ __forceinline__ void fwd_block(
    const float4 (&X)[10], const int4 (&M)[2],
    float (&dp)[5], const float (&tr)[5][5],
    uint16_t* __restrict__ dst)
{
    float xf[40];
#pragma unroll
    for (int q = 0; q < 10; ++q) {
        xf[4*q] = X[q].x; xf[4*q+1] = X[q].y; xf[4*q+2] = X[q].z; xf[4*q+3] = X[q].w;
    }
    int ml[8];
#pragma unroll
    for (int q = 0; q < 2; ++q) {
        ml[4*q] = M[q].x; ml[4*q+1] = M[q].y; ml[4*q+2] = M[q].z; ml[4*q+3] = M[q].w;
    }
    uint32_t acc[4];
#pragma unroll
    for (int q = 0; q < 4; ++q) acc[q] = 0;
#pragma unroll
    for (int l = 0; l < 8; ++l) {
        uint32_t pk;
        if (l < LSTART) {
            pk = IDENT;                       // t==0 slot, never applied
        } else {
            const bool mm = (ml[l] != 0);
            float nd[5]; uint32_t pc = 0;
#pragma unroll
            for (int j = 0; j < 5; ++j) {
                float s0 = dp[0] + tr[0][j];
                float s1 = dp[1] + tr[1][j];
                float s2 = dp[2] + tr[2][j];
                float s3 = dp[3] + tr[3][j];
                float s4 = dp[4] + tr[4][j];
                float m = fmaxf(fmaxf(fmaxf(s0, s1), fmaxf(s2, s3)), s4);
                int a = (s0 == m) ? 0 : ((s1 == m) ? 1 : ((s2 == m) ? 2 : ((s3 == m) ? 3 : 4)));
                nd[j] = m + xf[5*l + j];
                pc |= ((uint32_t)a) << (3*j);
            }
#pragma unroll
            for (int j = 0; j < 5; ++j) dp[j] = mm ? nd[j] : dp[j];
            pk = mm ? pc : IDENT;
        }
        acc[l >> 1] |= pk << (16 * (l & 1));
    }
    uint4 st; st.x = acc[0]; st.y = acc[1]; st.z = acc[2]; st.w = acc[3];
    *(uint4*)dst = st;
}

// ================= kernels =================

__global__ __launch_bounds__(256) void k_compose(
    const float* __restrict__ x, const int* __restrict__ mask,
    const float* __restrict__ transform, float* __restrict__ A)
{
    int tid = blockIdx.x * 256 + threadIdx.x;
    int b = tid & (B_ - 1), c = tid >> 11;
    float tr[5][5];
#pragma unroll
    for (int i = 0; i < 5; ++i)
#pragma unroll
        for (int j = 0; j < 5; ++j) tr[i][j] = transform[i*TD + j];

    const float* xb = x + ((size_t)b * T_ + (size_t)c * L_) * 5;
    const int*   mb = mask + (size_t)b * T_ + c * L_;

    float Am[5][5];
#pragma unroll
    for (int i = 0; i < 5; ++i)
#pragma unroll
        for (int j = 0; j < 5; ++j) Am[i][j] = (i == j) ? 0.f : -1e30f;

    float4 XA[10], XB[10]; int4 MA[2], MB[2];
    loadx(xb, mb, 0, XA, MA);
    loadx(xb, mb, 1, XB, MB);
    if (c == 0) compose_block<1>(XA, MA, Am, tr); else compose_block<0>(XA, MA, Am, tr);
    for (int k = 1; k < NB - 1; k += 2) {
        loadx(xb, mb, k + 1, XA, MA);
        compose_block<0>(XB, MB, Am, tr);
        loadx(xb, mb, k + 2, XB, MB);
        compose_block<0>(XA, MA, Am, tr);
    }
    compose_block<0>(XB, MB, Am, tr);

#pragma unroll
    for (int i = 0; i < 5; ++i)
#pragma unroll
        for (int j = 0; j < 5; ++j)
            A[((size_t)c * 25 + i*5 + j) * B_ + b] = Am[i][j];
}

__global__ __launch_bounds__(64) void k_scan(
    const float* __restrict__ x, const float* __restrict__ transform,
    const float* __restrict__ A, float* __restrict__ dps)
{
    int b = blockIdx.x * 64 + threadIdx.x;
    float dp[5];
#pragma unroll
    for (int j = 0; j < 5; ++j) dp[j] = x[(size_t)b * T_ * 5 + j] + transform[5*TD + j];
#pragma unroll
    for (int j = 0; j < 5; ++j) dps[(size_t)j * B_ + b] = dp[j];
#pragma unroll
    for (int c = 0; c < NCH - 1; ++c) {
        float a[25];
#pragma unroll
        for (int k = 0; k < 25; ++k) a[k] = A[((size_t)c * 25 + k) * B_ + b];
        float nd[5];
#pragma unroll
        for (int j = 0; j < 5; ++j) {
            float v = dp[0] + a[j];
            v = fmaxf(v, dp[1] + a[5 + j]);
            v = fmaxf(v, dp[2] + a[10 + j]);
            v = fmaxf(v, dp[3] + a[15 + j]);
            v = fmaxf(v, dp[4] + a[20 + j]);
            nd[j] = v;
        }
#pragma unroll
        for (int j = 0; j < 5; ++j) { dp[j] = nd[j]; dps[((size_t)(c+1) * 5 + j) * B_ + b] = dp[j]; }
    }
}

__global__ __launch_bounds__(256) void k_fwd(
    const float* __restrict__ x, const int* __restrict__ mask,
    const float* __restrict__ transform, const float* __restrict__ dps,
    uint16_t* __restrict__ bp, uint16_t* __restrict__ sigma,
    float* __restrict__ out, int* __restrict__ lastc)
{
    int tid = blockIdx.x * 256 + threadIdx.x;
    int b = tid & (B_ - 1), c = tid >> 11;
    float tr[5][5];
#pragma unroll
    for (int i = 0; i < 5; ++i)
#pragma unroll
        for (int j = 0; j < 5; ++j) tr[i][j] = transform[i*TD + j];

    const float* xb  = x + ((size_t)b * T_ + (size_t)c * L_) * 5;
    const int*   mb  = mask + (size_t)b * T_ + c * L_;
    uint16_t*    bpb = bp + (size_t)b * T_ + c * L_;

    float dp[5];
#pragma unroll
    for (int j = 0; j < 5; ++j) dp[j] = dps[((size_t)c * 5 + j) * B_ + b];

    float4 XA[10], XB[10]; int4 MA[2], MB[2];
    loadx(xb, mb, 0, XA, MA);
    loadx(xb, mb, 1, XB, MB);
    if (c == 0) fwd_block<1>(XA, MA, dp, tr, bpb); else fwd_block<0>(XA, MA, dp, tr, bpb);
    for (int k = 1; k < NB - 1; k += 2) {
        loadx(xb, mb, k + 1, XA, MA);
        fwd_block<0>(XB, MB, dp, tr, bpb + (size_t)k * 8);
        loadx(xb, mb, k + 2, XB, MB);
        fwd_block<0>(XA, MA, dp, tr, bpb + (size_t)(k + 1) * 8);
    }
    fwd_block<0>(XB, MB, dp, tr, bpb + (size_t)(NB - 1) * 8);

    if (c == NCH - 1) {
        float best = dp[0] + transform[0*TD + 6];
        int   last = 0;
#pragma unroll
        for (int j = 1; j < 5; ++j) {
            float sc = dp[j] + transform[j*TD + 6];
            if (sc > best) { best = sc; last = j; }
        }
        out[b]   = best;
        lastc[b] = last;
    }

    // sigma_c: compose own chunk's backpointers backward (re-read own stores, L2-hot)
    uint32_t ww[32];
    const uint4* wp = (const uint4*)bpb;
#pragma unroll
    for (int q = 0; q < 8; ++q) {
        uint4 w = wp[q];
        ww[4*q] = w.x; ww[4*q+1] = w.y; ww[4*q+2] = w.z; ww[4*q+3] = w.w;
    }
    int i0 = 0, i1 = 1, i2 = 2, i3 = 3, i4 = 4;
#pragma unroll
    for (int l = L_ - 1; l >= 0; --l) {
        uint32_t p = (ww[l >> 1] >> (16 * (l & 1))) & 0xFFFFu;
        i0 = (p >> (3*i0)) & 7;
        i1 = (p >> (3*i1)) & 7;
        i2 = (p >> (3*i2)) & 7;
        i3 = (p >> (3*i3)) & 7;
        i4 = (p >> (3*i4)) & 7;
    }
    sigma[(size_t)c * B_ + b] =
        (uint16_t)(i0 | (i1 << 3) | (i2 << 6) | (i3 << 9) | (i4 << 12));
}

__global__ __launch_bounds__(64) void k_back(
    const int* __restrict__ lastc, const uint16_t* __restrict__ sigma,
    uint8_t* __restrict__ endc)
{
    int b = blockIdx.x * 64 + threadIdx.x;
    uint32_t sg[NCH];
#pragma unroll
    for (int c = 0; c < NCH; ++c) sg[c] = sigma[(size_t)c * B_ + b];
    int e = lastc[b];
#pragma unroll
    for (int c = NCH - 1; c >= 1; --c) {
        endc[(size_t)c * B_ + b] = (uint8_t)e;
        e = (sg[c] >> (3*e)) & 7;
    }
    endc[b] = (uint8_t)e;
}

__global__ __launch_bounds__(256) void k_path(
    const uint16_t* __restrict__ bp, const uint8_t* __restrict__ endc,
    float* __restrict__ out)
{
    int tid = blockIdx.x * 256 + threadIdx.x;
    int b = tid & (B_ - 1), c = tid >> 11;
    int idx = endc[(size_t)c * B_ + b];
    const uint4* wp = (const uint4*)(bp + (size_t)b * T_ + c * L_);
    uint32_t ww[32];
#pragma unroll
    for (int q = 0; q < 8; ++q) {
        uint4 w = wp[q];
        ww[4*q] = w.x; ww[4*q+1] = w.y; ww[4*q+2] = w.z; ww[4*q+3] = w.w;
    }
    float pv[L_];
#pragma unroll
    for (int l = L_ - 1; l >= 0; --l) {
        pv[l] = (float)idx;
        uint32_t p = (ww[l >> 1] >> (16 * (l & 1))) & 0xFFFFu;
        idx = (p >> (3*idx)) & 7;
    }
    float* path = out + B_ + (size_t)b * T_ + c * L_;
#pragma unroll
    for (int q = 0; q < 16; ++q) {
        float4 v; v.x = pv[4*q]; v.y = pv[4*q+1]; v.z = pv[4*q+2]; v.w = pv[4*q+3];
        ((float4*)path)[q] = v;
    }
}

extern "C" void kernel_launch(void* const* d_in, const int* in_sizes, int n_in,
                              void* d_out, int out_size, void* d_ws, size_t ws_size,
                              hipStream_t stream) {
    const float* x         = (const float*)d_in[0];
    const int*   mask      = (const int*)d_in[1];
    const float* transform = (const float*)d_in[2];
    float*       out       = (float*)d_out;

    uint8_t* w = (uint8_t*)d_ws;
    // layout (16-byte aligned offsets), total ~15.7 MiB
    uint16_t* bp    = (uint16_t*)(w);                               // 8 MiB
    float*    A     = (float*)  (w + (8u<<20));                     // 6.25 MiB
    float*    dps   = (float*)  (w + (8u<<20) + 6553600u);          // 1.25 MiB
    uint16_t* sig   = (uint16_t*)(w + (8u<<20) + 6553600u + 1310720u);          // 128 KiB
    uint8_t*  endc  = (uint8_t*) (w + (8u<<20) + 6553600u + 1310720u + 131072u); // 64 KiB
    int*      lastc = (int*)     (w + (8u<<20) + 6553600u + 1310720u + 131072u + 65536u); // 8 KiB

    hipLaunchKernelGGL(k_compose, dim3(B_*NCH/256), dim3(256), 0, stream, x, mask, transform, A);
    hipLaunchKernelGGL(k_scan,    dim3(B_/64),      dim3(64),  0, stream, x, transform, A, dps);
    hipLaunchKernelGGL(k_fwd,     dim3(B_*NCH/256), dim3(256), 0, stream, x, mask, transform, dps,
                       bp, sig, out, lastc);
    hipLaunchKernelGGL(k_back,    dim3(B_/64),      dim3(64),  0, stream, lastc, sig, endc);
    hipLaunchKernelGGL(k_path,    dim3(B_*NCH/256), dim3(256), 0, stream, bp, endc, out);
}